// Round 2
// baseline (523.874 us; speedup 1.0000x reference)
//
#include <hip/hip_runtime.h>
#include <stdint.h>

// ---------------- types / helpers ----------------
typedef short bf16x8 __attribute__((ext_vector_type(8)));
typedef float f32x4 __attribute__((ext_vector_type(4)));
typedef unsigned short u16;
typedef unsigned short u16x4 __attribute__((ext_vector_type(4)));

#define AS1 __attribute__((address_space(1)))
#define AS3 __attribute__((address_space(3)))

__device__ __forceinline__ void gll16(const void* g, void* l) {
  // async global->LDS, 16B per lane, LDS dest = wave-uniform base + lane*16
  __builtin_amdgcn_global_load_lds((const AS1 uint32_t*)g, (AS3 uint32_t*)l, 16, 0, 0);
}

__device__ __forceinline__ f32x4 mfma16(bf16x8 a, bf16x8 b, f32x4 c) {
  return __builtin_amdgcn_mfma_f32_16x16x32_bf16(a, b, c, 0, 0, 0);
}

__device__ __forceinline__ u16 f2bf(float f) {
  union { float f; uint32_t u; } c; c.f = f;
  uint32_t r = c.u + 0x7FFFu + ((c.u >> 16) & 1u);   // RNE
  return (u16)(r >> 16);
}
__device__ __forceinline__ float bf2f(u16 h) {
  union { uint32_t u; float f; } c; c.u = ((uint32_t)h) << 16; return c.f;
}

// ---------------- cast fp32 -> bf16 ----------------
__global__ __launch_bounds__(256) void k_cast(const float* __restrict__ in, u16* __restrict__ out) {
  int i = (blockIdx.x * 256 + threadIdx.x) * 4;
  float4 v = *(const float4*)(in + i);
  u16x4 r; r.x = f2bf(v.x); r.y = f2bf(v.y); r.z = f2bf(v.z); r.w = f2bf(v.w);
  *(u16x4*)(out + i) = r;
}

// ---------------- transpose fp32 (R x C) -> bf16 (C x R) ----------------
__global__ __launch_bounds__(1024) void k_transpose(const float* __restrict__ src, u16* __restrict__ dst,
                                                    int R, int C) {
  __shared__ float t[32][33];
  int tx = threadIdx.x, ty = threadIdx.y;
  t[ty][tx] = src[(size_t)(blockIdx.y * 32 + ty) * C + blockIdx.x * 32 + tx];
  __syncthreads();
  dst[(size_t)(blockIdx.x * 32 + ty) * R + blockIdx.y * 32 + tx] = f2bf(t[tx][ty]);
}

// ---------------- fused QKV GEMM: A[16384x1024] * Wt[3072x1024]^T ----------------
// Q (scaled 1/8) -> [b][h][s][d]; K -> [b][h][s][d]; V -> TRANSPOSED [b][h][d][s]
__global__ __launch_bounds__(256) void k_gemm_qkv(
    const u16* __restrict__ A, const u16* __restrict__ Bt,
    const float* __restrict__ bq, const float* __restrict__ bk, const float* __restrict__ bv,
    u16* __restrict__ Qb, u16* __restrict__ Kb, u16* __restrict__ Vbt)
{
  __shared__ u16 As[128 * 32];
  __shared__ u16 Bs[128 * 32];
  int tid = threadIdx.x, lane = tid & 63, w = tid >> 6;
  int wm = w >> 1, wn = w & 1;
  int m0 = blockIdx.y * 128, n0 = blockIdx.x * 128;

  // staging: wave w stages chunks {2w,2w+1} of A and B. chunk = 16 rows x 32 k.
  int l4 = lane >> 2;
  int p = (lane & 3) ^ ((lane >> 3) & 3);          // swizzled global k-chunk (8 elems)
  const u16* Ag0 = A + (size_t)(m0 + w * 32 + l4) * 1024 + p * 8;
  const u16* Ag1 = A + (size_t)(m0 + w * 32 + 16 + l4) * 1024 + p * 8;
  const u16* Bg0 = Bt + (size_t)(n0 + w * 32 + l4) * 1024 + p * 8;
  const u16* Bg1 = Bt + (size_t)(n0 + w * 32 + 16 + l4) * 1024 + p * 8;
  u16* La0 = As + w * 1024; u16* La1 = As + w * 1024 + 512;
  u16* Lb0 = Bs + w * 1024; u16* Lb1 = Bs + w * 1024 + 512;

  int mm = lane & 15, quad = lane >> 4;
  int sw = quad ^ ((mm >> 1) & 3);                  // swizzled LDS chunk for frag reads
  const bf16x8* pa[4]; const bf16x8* pb[4];
#pragma unroll
  for (int t = 0; t < 4; ++t) {
    pa[t] = (const bf16x8*)(As + (wm * 64 + t * 16 + mm) * 32 + sw * 8);
    pb[t] = (const bf16x8*)(Bs + (wn * 64 + t * 16 + mm) * 32 + sw * 8);
  }

  f32x4 acc[4][4];
#pragma unroll
  for (int i = 0; i < 4; ++i)
#pragma unroll
    for (int j = 0; j < 4; ++j) acc[i][j] = (f32x4){0.f, 0.f, 0.f, 0.f};

  for (int kt = 0; kt < 32; ++kt) {
    int ko = kt * 32;
    gll16(Ag0 + ko, La0); gll16(Ag1 + ko, La1);
    gll16(Bg0 + ko, Lb0); gll16(Bg1 + ko, Lb1);
    __syncthreads();
    bf16x8 a[4], b[4];
#pragma unroll
    for (int t = 0; t < 4; ++t) { a[t] = *pa[t]; b[t] = *pb[t]; }
#pragma unroll
    for (int i = 0; i < 4; ++i)
#pragma unroll
      for (int j = 0; j < 4; ++j) acc[i][j] = mfma16(a[i], b[j], acc[i][j]);
    __syncthreads();
  }

  int sel = n0 >> 10;                                // uniform per block: 0=Q,1=K,2=V
  const float* bias = sel == 0 ? bq : (sel == 1 ? bk : bv);
  float scl = sel == 0 ? 0.125f : 1.0f;
#pragma unroll
  for (int j = 0; j < 4; ++j) {
    int ng = n0 + wn * 64 + j * 16 + mm;
    int h = (ng >> 6) & 15, d = ng & 63;
    float bval = bias[ng & 1023];
#pragma unroll
    for (int i = 0; i < 4; ++i)
#pragma unroll
      for (int r = 0; r < 4; ++r) {
        int mg = m0 + wm * 64 + i * 16 + quad * 4 + r;
        int b_ = mg >> 12, s = mg & 4095;
        float v = (acc[i][j][r] + bval) * scl;
        if (sel == 0)      Qb [((size_t)(b_ * 16 + h) * 4096 + s) * 64 + d] = f2bf(v);
        else if (sel == 1) Kb [((size_t)(b_ * 16 + h) * 4096 + s) * 64 + d] = f2bf(v);
        else               Vbt[((size_t)(b_ * 16 + h) * 64 + d) * 4096 + s] = f2bf(v);
      }
  }
}

// ---------------- output GEMM: X[16384x1024] * Wot[1024x1024]^T + bo -> fp32 ----------------
__global__ __launch_bounds__(256) void k_gemm_out(
    const u16* __restrict__ A, const u16* __restrict__ Bt,
    const float* __restrict__ bo, float* __restrict__ out)
{
  __shared__ u16 As[128 * 32];
  __shared__ u16 Bs[128 * 32];
  int tid = threadIdx.x, lane = tid & 63, w = tid >> 6;
  int wm = w >> 1, wn = w & 1;
  int m0 = blockIdx.y * 128, n0 = blockIdx.x * 128;
  int l4 = lane >> 2;
  int p = (lane & 3) ^ ((lane >> 3) & 3);
  const u16* Ag0 = A + (size_t)(m0 + w * 32 + l4) * 1024 + p * 8;
  const u16* Ag1 = A + (size_t)(m0 + w * 32 + 16 + l4) * 1024 + p * 8;
  const u16* Bg0 = Bt + (size_t)(n0 + w * 32 + l4) * 1024 + p * 8;
  const u16* Bg1 = Bt + (size_t)(n0 + w * 32 + 16 + l4) * 1024 + p * 8;
  u16* La0 = As + w * 1024; u16* La1 = As + w * 1024 + 512;
  u16* Lb0 = Bs + w * 1024; u16* Lb1 = Bs + w * 1024 + 512;
  int mm = lane & 15, quad = lane >> 4;
  int sw = quad ^ ((mm >> 1) & 3);
  const bf16x8* pa[4]; const bf16x8* pb[4];
#pragma unroll
  for (int t = 0; t < 4; ++t) {
    pa[t] = (const bf16x8*)(As + (wm * 64 + t * 16 + mm) * 32 + sw * 8);
    pb[t] = (const bf16x8*)(Bs + (wn * 64 + t * 16 + mm) * 32 + sw * 8);
  }
  f32x4 acc[4][4];
#pragma unroll
  for (int i = 0; i < 4; ++i)
#pragma unroll
    for (int j = 0; j < 4; ++j) acc[i][j] = (f32x4){0.f, 0.f, 0.f, 0.f};
  for (int kt = 0; kt < 32; ++kt) {
    int ko = kt * 32;
    gll16(Ag0 + ko, La0); gll16(Ag1 + ko, La1);
    gll16(Bg0 + ko, Lb0); gll16(Bg1 + ko, Lb1);
    __syncthreads();
    bf16x8 a[4], b[4];
#pragma unroll
    for (int t = 0; t < 4; ++t) { a[t] = *pa[t]; b[t] = *pb[t]; }
#pragma unroll
    for (int i = 0; i < 4; ++i)
#pragma unroll
      for (int j = 0; j < 4; ++j) acc[i][j] = mfma16(a[i], b[j], acc[i][j]);
    __syncthreads();
  }
#pragma unroll
  for (int j = 0; j < 4; ++j) {
    int ng = n0 + wn * 64 + j * 16 + mm;
    float bval = bo[ng];
#pragma unroll
    for (int i = 0; i < 4; ++i)
#pragma unroll
      for (int r = 0; r < 4; ++r) {
        int mg = m0 + wm * 64 + i * 16 + quad * 4 + r;
        out[(size_t)mg * 1024 + ng] = acc[i][j][r] + bval;
      }
  }
}

// ---------------- per-block key sums ----------------
__global__ __launch_bounds__(64) void k_sumkey(const u16* __restrict__ Kb, float* __restrict__ sumk) {
  int d = threadIdx.x, n = blockIdx.x, h = blockIdx.y, b = blockIdx.z;
  const u16* p = Kb + (((size_t)(b * 16 + h) * 4096) + n * 128) * 64 + d;
  float a0 = 0, a1 = 0, a2 = 0, a3 = 0;
  for (int s = 0; s < 128; s += 4) {
    a0 += bf2f(p[(s + 0) * 64]); a1 += bf2f(p[(s + 1) * 64]);
    a2 += bf2f(p[(s + 2) * 64]); a3 += bf2f(p[(s + 3) * 64]);
  }
  sumk[((size_t)(b * 32 + n) * 16 + h) * 64 + d] = (a0 + a1) + (a2 + a3);
}

// ---------------- sort logits: sumk[b][n][1024] @ w_sort[1024][32] + b_sort ----------------
__global__ __launch_bounds__(256) void k_sortmm(const float* __restrict__ sumk, const float* __restrict__ wsort,
                                                const float* __restrict__ bsort, float* __restrict__ so) {
  __shared__ float red[256];
  int n = blockIdx.x, b = blockIdx.y, t = threadIdx.x;
  int m = t & 31, kp = t >> 5;
  const float* row = sumk + (size_t)(b * 32 + n) * 1024;
  float acc = 0.f;
  for (int c = kp * 128; c < kp * 128 + 128; ++c) acc += row[c] * wsort[c * 32 + m];
  red[t] = acc;
  __syncthreads();
  if (t < 32) {
    float s = bsort[t];
#pragma unroll
    for (int q = 0; q < 8; ++q) s += red[q * 32 + t];
    so[(size_t)(b * 32 + n) * 32 + t] = s;
  }
}

// ---------------- Sinkhorn (5 iters) + clip + exp ----------------
__global__ __launch_bounds__(32) void k_sinkhorn(const float* __restrict__ so, float* __restrict__ perm) {
  __shared__ float A[32][33];
  int b = blockIdx.x, t = threadIdx.x;
  for (int i = 0; i < 32; ++i) A[i][t] = so[(size_t)(b * 32 + i) * 32 + t];
  __syncthreads();
  for (int it = 0; it < 5; ++it) {
    { // row LSE (axis=2)
      float mx = -1e30f;
      for (int j = 0; j < 32; ++j) mx = fmaxf(mx, A[t][j]);
      float s = 0.f;
      for (int j = 0; j < 32; ++j) s += __expf(A[t][j] - mx);
      float l = mx + __logf(s);
      for (int j = 0; j < 32; ++j) A[t][j] -= l;
    }
    __syncthreads();
    { // col LSE (axis=1)
      float mx = -1e30f;
      for (int j = 0; j < 32; ++j) mx = fmaxf(mx, A[j][t]);
      float s = 0.f;
      for (int j = 0; j < 32; ++j) s += __expf(A[j][t] - mx);
      float l = mx + __logf(s);
      for (int j = 0; j < 32; ++j) A[j][t] -= l;
    }
    __syncthreads();
  }
  for (int i = 0; i < 32; ++i)
    perm[(size_t)(b * 32 + i) * 32 + t] = __expf(fminf(fmaxf(A[i][t], -1.f), 1.f));
}

// ---------------- K mix: Ksort[b][h][n][128s][64d] = sum_m perm[n][m] * K[b][h][m*128+s][d]
__global__ __launch_bounds__(256) void k_mix_k(
    const u16* __restrict__ Kb, const float* __restrict__ perm, u16* __restrict__ Ksort)
{
  __shared__ float P[32][32];
  int b = blockIdx.z, h = blockIdx.y, sg = blockIdx.x;
  int tid = threadIdx.x;
#pragma unroll
  for (int i = 0; i < 4; ++i) {
    int idx = i * 256 + tid;
    P[idx >> 5][idx & 31] = perm[b * 1024 + idx];
  }
  __syncthreads();
  int ss = sg * 4 + (tid >> 6), d = tid & 63;
  const u16* Kg = Kb + (size_t)(b * 16 + h) * 262144;
  float xk[32];
#pragma unroll
  for (int m = 0; m < 32; ++m) xk[m] = bf2f(Kg[(size_t)(m * 128 + ss) * 64 + d]);
  size_t tbase = (size_t)((b * 16 + h) * 32) * 8192;
#pragma unroll
  for (int nn = 0; nn < 32; ++nn) {
    float sk = 0.f;
#pragma unroll
    for (int m4 = 0; m4 < 8; ++m4) {
      float4 pv = *(const float4*)&P[nn][m4 * 4];
      sk += pv.x * xk[m4 * 4 + 0] + pv.y * xk[m4 * 4 + 1] + pv.z * xk[m4 * 4 + 2] + pv.w * xk[m4 * 4 + 3];
    }
    Ksort[tbase + (size_t)nn * 8192 + ss * 64 + d] = f2bf(sk);
  }
}

// ---------------- V mix (transposed): Vsort[b][h][n][64d][128s] from Vbt[b][h][d][s]
__global__ __launch_bounds__(256) void k_mix_v(
    const u16* __restrict__ Vbt, const float* __restrict__ perm, u16* __restrict__ Vsort)
{
  __shared__ float P[32][32];
  int b = blockIdx.z, h = blockIdx.y, dg = blockIdx.x;   // dg in [0,32)
  int tid = threadIdx.x;
#pragma unroll
  for (int i = 0; i < 4; ++i) {
    int idx = i * 256 + tid;
    P[idx >> 5][idx & 31] = perm[b * 1024 + idx];
  }
  __syncthreads();
  int d = dg * 2 + (tid >> 7), ss = tid & 127;
  const u16* Vg = Vbt + ((size_t)(b * 16 + h) * 64 + d) * 4096;
  float xv[32];
#pragma unroll
  for (int m = 0; m < 32; ++m) xv[m] = bf2f(Vg[m * 128 + ss]);
  size_t tbase = (size_t)((b * 16 + h) * 32) * 8192;
#pragma unroll
  for (int nn = 0; nn < 32; ++nn) {
    float sv = 0.f;
#pragma unroll
    for (int m4 = 0; m4 < 8; ++m4) {
      float4 pv = *(const float4*)&P[nn][m4 * 4];
      sv += pv.x * xv[m4 * 4 + 0] + pv.y * xv[m4 * 4 + 1] + pv.z * xv[m4 * 4 + 2] + pv.w * xv[m4 * 4 + 3];
    }
    Vsort[tbase + (size_t)nn * 8192 + d * 128 + ss] = f2bf(sv);
  }
}

// ---------------- attention per (b,n,h): softmax(Q Kcat^T) Vcat ----------------
__global__ __launch_bounds__(256, 2) void k_attn(
    const u16* __restrict__ Qb, const u16* __restrict__ Kb, const u16* __restrict__ Ksort,
    const u16* __restrict__ Vbt, const u16* __restrict__ Vsort, u16* __restrict__ X)
{
  __shared__ u16 Ks[16384];    // 256 kk x 64 d (swizzled); later overlaid by per-wave P
  __shared__ u16 Vlo[8192];    // 64 d x 128 kk (orig half, swizzled)
  __shared__ u16 Vhi[8192];    // 64 d x 128 kk (sorted half, swizzled)
  int tid = threadIdx.x, lane = tid & 63, w = tid >> 6;
  int n = blockIdx.x, h = blockIdx.y, b = blockIdx.z;
  size_t bh = (size_t)(b * 16 + h);
  size_t tileK = bh * 32 + n;

  { // stage Kcat rows: [0,128) from Kb, [128,256) from Ksort. chunk = 8 rows x 64 u16.
    int l8 = lane >> 3, sl8 = lane & 7;
    const u16* Korig = Kb + (bh * 4096 + (size_t)n * 128) * 64;
    const u16* Ksrt  = Ksort + tileK * 8192;
#pragma unroll
    for (int c = 0; c < 8; ++c) {
      int cc = w * 8 + c;
      int r = cc * 8 + l8;
      int pk = sl8 ^ (r & 7);
      const u16* src = (cc < 16) ? (Korig + (size_t)r * 64 + pk * 8)
                                 : (Ksrt + (size_t)(r - 128) * 64 + pk * 8);
      gll16(src, Ks + cc * 512);
    }
    // stage V panels: chunk = 4 d-rows x 128 u16.
    int l16 = lane >> 4, sl16 = lane & 15;
    const u16* Vorig = Vbt + bh * 262144 + (size_t)n * 128;
    const u16* Vsrt  = Vsort + tileK * 8192;
#pragma unroll
    for (int c = 0; c < 4; ++c) {
      int cc = w * 4 + c;
      int d = cc * 4 + l16;
      int pv = sl16 ^ (d & 15);
      gll16(Vorig + (size_t)d * 4096 + pv * 8, Vlo + cc * 512);
      gll16(Vsrt + (size_t)d * 128 + pv * 8, Vhi + cc * 512);
    }
  }

  int mm = lane & 15, quad = lane >> 4;
  bf16x8 qf[2][2];
  {
    size_t qrow = bh * 4096 + n * 128 + w * 32;
#pragma unroll
    for (int mt = 0; mt < 2; ++mt)
#pragma unroll
      for (int ks = 0; ks < 2; ++ks)
        qf[mt][ks] = *(const bf16x8*)(Qb + (qrow + mt * 16 + mm) * 64 + ks * 32 + quad * 8);
  }
  __syncthreads();

  // S = Qs @ Kcat^T  (wave w owns q rows [w*32, w*32+32))
  f32x4 S[2][16];
#pragma unroll
  for (int mt = 0; mt < 2; ++mt)
#pragma unroll
    for (int nt = 0; nt < 16; ++nt) S[mt][nt] = (f32x4){0.f, 0.f, 0.f, 0.f};
#pragma unroll
  for (int nt = 0; nt < 16; ++nt) {
    int kk = nt * 16 + mm;
#pragma unroll
    for (int ks = 0; ks < 2; ++ks) {
      int ch = (ks * 4 + quad) ^ (kk & 7);
      bf16x8 bk = *(const bf16x8*)(Ks + kk * 64 + ch * 8);
      S[0][nt] = mfma16(qf[0][ks], bk, S[0][nt]);
      S[1][nt] = mfma16(qf[1][ks], bk, S[1][nt]);
    }
  }

  // softmax over kk (C-layout: row = quad*4+r, col = mm across nt)
  float mx[2][4], ls[2][4];
#pragma unroll
  for (int mt = 0; mt < 2; ++mt)
#pragma unroll
    for (int r = 0; r < 4; ++r) {
      float v = S[mt][0][r];
#pragma unroll
      for (int nt = 1; nt < 16; ++nt) v = fmaxf(v, S[mt][nt][r]);
#pragma unroll
      for (int o = 1; o < 16; o <<= 1) v = fmaxf(v, __shfl_xor(v, o));
      mx[mt][r] = v;
    }
#pragma unroll
  for (int mt = 0; mt < 2; ++mt)
#pragma unroll
    for (int nt = 0; nt < 16; ++nt)
#pragma unroll
      for (int r = 0; r < 4; ++r)
        S[mt][nt][r] = __expf(S[mt][nt][r] - mx[mt][r]);
#pragma unroll
  for (int mt = 0; mt < 2; ++mt)
#pragma unroll
    for (int r = 0; r < 4; ++r) {
      float s = 0.f;
#pragma unroll
      for (int nt = 0; nt < 16; ++nt) s += S[mt][nt][r];
#pragma unroll
      for (int o = 1; o < 16; o <<= 1) s += __shfl_xor(s, o);
      ls[mt][r] = s;
    }

  __syncthreads();   // all waves done reading Ks before overlaying with P

  // PV in two kk halves; P (bf16) round-trips through per-wave LDS region over Ks
  u16* Pw = Ks + w * 4096;   // 32 q-rows x 128 kk per half (8KB per wave)
  f32x4 O[2][4];
#pragma unroll
  for (int mt = 0; mt < 2; ++mt)
#pragma unroll
    for (int dt = 0; dt < 4; ++dt) O[mt][dt] = (f32x4){0.f, 0.f, 0.f, 0.f};

#pragma unroll
  for (int half = 0; half < 2; ++half) {
    const u16* Vp = half == 0 ? Vlo : Vhi;
#pragma unroll
    for (int mt = 0; mt < 2; ++mt)
#pragma unroll
      for (int nt8 = 0; nt8 < 8; ++nt8) {
        int nt = half * 8 + nt8;
        int kkl = nt8 * 16 + mm;
#pragma unroll
        for (int r = 0; r < 4; ++r) {
          int q = mt * 16 + quad * 4 + r;
          int ch = (kkl >> 3) ^ (q & 15);
          Pw[q * 128 + ch * 8 + (kkl & 7)] = f2bf(S[mt][nt][r]);
        }
      }
#pragma unroll
    for (int ksl = 0; ksl < 4; ++ksl) {
      bf16x8 pa[2];
#pragma unroll
      for (int mt = 0; mt < 2; ++mt) {
        int q = mt * 16 + mm;
        int ch = (ksl * 4 + quad) ^ (q & 15);
        pa[mt] = *(const bf16x8*)(Pw + q * 128 + ch * 8);
      }
#pragma unroll
      for (int dt = 0; dt < 4; ++dt) {
        int d = dt * 16 + mm;
        int ch = (ksl * 4 + quad) ^ (d & 15);
        bf16x8 vb = *(const bf16x8*)(Vp + d * 128 + ch * 8);
        O[0][dt] = mfma16(pa[0], vb, O[0][dt]);
        O[1][dt] = mfma16(pa[1], vb, O[1][dt]);
      }
    }
  }

  // epilogue: normalize and write X[b*4096+s][h*64+d] (bf16)
#pragma unroll
  for (int mt = 0; mt < 2; ++mt)
#pragma unroll
    for (int dt = 0; dt < 4; ++dt)
#pragma unroll
      for (int r = 0; r < 4; ++r) {
        int q = w * 32 + mt * 16 + quad * 4 + r;
        float val = O[mt][dt][r] / ls[mt][r];
        size_t row = (size_t)b * 4096 + n * 128 + q;
        X[row * 1024 + h * 64 + dt * 16 + mm] = f2bf(val);
      }
}

// ---------------- launch ----------------
extern "C" void kernel_launch(void* const* d_in, const int* in_sizes, int n_in,
                              void* d_out, int out_size, void* d_ws, size_t ws_size,
                              hipStream_t stream) {
  const float* inq   = (const float*)d_in[0];
  const float* wq    = (const float*)d_in[1];
  const float* bq    = (const float*)d_in[2];
  const float* wk    = (const float*)d_in[3];
  const float* bk    = (const float*)d_in[4];
  const float* wv    = (const float*)d_in[5];
  const float* bv    = (const float*)d_in[6];
  const float* wsort = (const float*)d_in[7];
  const float* bsort = (const float*)d_in[8];
  const float* wo    = (const float*)d_in[9];
  const float* bo    = (const float*)d_in[10];
  float* out = (float*)d_out;

  char* ws = (char*)d_ws;
  size_t off = 0;
  auto alloc = [&](size_t bytes) { char* p = ws + off; off += (bytes + 255) & ~(size_t)255; return p; };
  u16*  Qb    = (u16*)alloc(33554432);   // [4][16][4096][64] bf16, pre-scaled 1/8
  u16*  Kb    = (u16*)alloc(33554432);   // K [4][16][4096][64]
  u16*  Vbt   = (u16*)alloc(33554432);   // V transposed [4][16][64][4096]
  u16*  Ksort = (u16*)alloc(33554432);   // sorted K [4][16][32][128][64]
  u16*  Vsort = (u16*)alloc(33554432);   // sorted V^T [4][16][32][64][128]
  u16*  Abf   = (u16*)alloc(33554432);   // bf16 input; later aliased as X
  u16*  Wqkvt = (u16*)alloc(6291456);    // [3072][1024] bf16 (B^T)
  u16*  Wot   = (u16*)alloc(2097152);    // [1024][1024] bf16 (B^T)
  float* sumk = (float*)alloc(524288);   // [4][32][1024]
  float* so   = (float*)alloc(16384);    // [4][32][32]
  float* perm = (float*)alloc(16384);    // [4][32][32]
  u16*  X = Abf;   // alias: attention output over Abf (dead after k_gemm_qkv)
  // total: 200.6 MB

  k_cast<<<16384, 256, 0, stream>>>(inq, Abf);
  dim3 tb(32, 32);
  k_transpose<<<dim3(32, 32), tb, 0, stream>>>(wq, Wqkvt,                   1024, 1024);
  k_transpose<<<dim3(32, 32), tb, 0, stream>>>(wk, Wqkvt + 1024 * 1024,     1024, 1024);
  k_transpose<<<dim3(32, 32), tb, 0, stream>>>(wv, Wqkvt + 2 * 1024 * 1024, 1024, 1024);
  k_transpose<<<dim3(32, 32), tb, 0, stream>>>(wo, Wot,                     1024, 1024);
  k_gemm_qkv<<<dim3(24, 128), 256, 0, stream>>>(Abf, Wqkvt, bq, bk, bv, Qb, Kb, Vbt);
  k_sumkey<<<dim3(32, 16, 4), 64, 0, stream>>>(Kb, sumk);
  k_sortmm<<<dim3(32, 4), 256, 0, stream>>>(sumk, wsort, bsort, so);
  k_sinkhorn<<<4, 32, 0, stream>>>(so, perm);
  k_mix_k<<<dim3(32, 16, 4), 256, 0, stream>>>(Kb, perm, Ksort);
  k_mix_v<<<dim3(32, 16, 4), 256, 0, stream>>>(Vbt, perm, Vsort);
  k_attn<<<dim3(32, 16, 4), 256, 0, stream>>>(Qb, Kb, Ksort, Vbt, Vsort, X);
  k_gemm_out<<<dim3(8, 128), 256, 0, stream>>>(X, Wot, bo, out);
}

// Round 3
// 501.889 us; speedup vs baseline: 1.0438x; 1.0438x over previous
//
#include <hip/hip_runtime.h>
#include <stdint.h>

// ---------------- types / helpers ----------------
typedef short bf16x8 __attribute__((ext_vector_type(8)));
typedef float f32x4 __attribute__((ext_vector_type(4)));
typedef unsigned short u16;
typedef unsigned short u16x4 __attribute__((ext_vector_type(4)));

#define AS1 __attribute__((address_space(1)))
#define AS3 __attribute__((address_space(3)))

__device__ __forceinline__ void gll16(const void* g, void* l) {
  // async global->LDS, 16B per lane, LDS dest = wave-uniform base + lane*16
  __builtin_amdgcn_global_load_lds((const AS1 uint32_t*)g, (AS3 uint32_t*)l, 16, 0, 0);
}

__device__ __forceinline__ f32x4 mfma16(bf16x8 a, bf16x8 b, f32x4 c) {
  return __builtin_amdgcn_mfma_f32_16x16x32_bf16(a, b, c, 0, 0, 0);
}

__device__ __forceinline__ u16 f2bf(float f) {
  union { float f; uint32_t u; } c; c.f = f;
  uint32_t r = c.u + 0x7FFFu + ((c.u >> 16) & 1u);   // RNE
  return (u16)(r >> 16);
}
__device__ __forceinline__ float bf2f(u16 h) {
  union { uint32_t u; float f; } c; c.u = ((uint32_t)h) << 16; return c.f;
}

// ---------------- cast fp32 -> bf16 ----------------
__global__ __launch_bounds__(256) void k_cast(const float* __restrict__ in, u16* __restrict__ out) {
  int i = (blockIdx.x * 256 + threadIdx.x) * 4;
  float4 v = *(const float4*)(in + i);
  u16x4 r; r.x = f2bf(v.x); r.y = f2bf(v.y); r.z = f2bf(v.z); r.w = f2bf(v.w);
  *(u16x4*)(out + i) = r;
}

// ---------------- 4 weight transposes fp32 (1024x1024) -> bf16 transposed, one dispatch ----------------
__global__ __launch_bounds__(1024) void k_transpose4(
    const float* __restrict__ wq, const float* __restrict__ wk,
    const float* __restrict__ wv, const float* __restrict__ wo,
    u16* __restrict__ Wqkvt, u16* __restrict__ Wot) {
  __shared__ float t[32][33];
  const float* src; u16* dst;
  int z = blockIdx.z;
  if (z == 0)      { src = wq; dst = Wqkvt; }
  else if (z == 1) { src = wk; dst = Wqkvt + 1024 * 1024; }
  else if (z == 2) { src = wv; dst = Wqkvt + 2 * 1024 * 1024; }
  else             { src = wo; dst = Wot; }
  int tx = threadIdx.x, ty = threadIdx.y;
  t[ty][tx] = src[(size_t)(blockIdx.y * 32 + ty) * 1024 + blockIdx.x * 32 + tx];
  __syncthreads();
  dst[(size_t)(blockIdx.x * 32 + ty) * 1024 + blockIdx.y * 32 + tx] = f2bf(t[tx][ty]);
}

// ---------------- fused QKV GEMM (BK=64): A[16384x1024] * Wt[3072x1024]^T ----------------
// Q (scaled 1/8) -> [b][h][s][d]; K -> [b][h][s][d]; V -> TRANSPOSED [b][h][d][s]
// K-blocks also emit per-block key sums (sumk) from fp32 accumulators.
__global__ __launch_bounds__(256) void k_gemm_qkv(
    const u16* __restrict__ A, const u16* __restrict__ Bt,
    const float* __restrict__ bq, const float* __restrict__ bk, const float* __restrict__ bv,
    u16* __restrict__ Qb, u16* __restrict__ Kb, u16* __restrict__ Vbt, float* __restrict__ sumk)
{
  __shared__ u16 As[128 * 64];   // 16 KB
  __shared__ u16 Bs[128 * 64];   // 16 KB
  int tid = threadIdx.x, lane = tid & 63, w = tid >> 6;
  int wm = w >> 1, wn = w & 1;
  int m0 = blockIdx.y * 128, n0 = blockIdx.x * 128;

  // staging: wave w stages chunks w*4+c (c=0..3), chunk = 8 rows x 64 k (1 KB).
  // lane: l8 = row-in-chunk, sl8 = LDS 16B-position; global k-chunk = sl8 ^ l8 (XOR swizzle).
  int l8 = lane >> 3, sl8 = lane & 7;
  int pg = sl8 ^ l8;
  const u16* Ag[4]; const u16* Bg[4]; u16* La[4]; u16* Lb[4];
#pragma unroll
  for (int c = 0; c < 4; ++c) {
    int cc = w * 4 + c, row = cc * 8 + l8;
    Ag[c] = A + (size_t)(m0 + row) * 1024 + pg * 8;
    Bg[c] = Bt + (size_t)(n0 + row) * 1024 + pg * 8;
    La[c] = As + cc * 512;
    Lb[c] = Bs + cc * 512;
  }

  int mm = lane & 15, quad = lane >> 4;
  f32x4 acc[4][4];
#pragma unroll
  for (int i = 0; i < 4; ++i)
#pragma unroll
    for (int j = 0; j < 4; ++j) acc[i][j] = (f32x4){0.f, 0.f, 0.f, 0.f};

  for (int kt = 0; kt < 16; ++kt) {
    int ko = kt * 64;
#pragma unroll
    for (int c = 0; c < 4; ++c) { gll16(Ag[c] + ko, La[c]); gll16(Bg[c] + ko, Lb[c]); }
    __syncthreads();
#pragma unroll
    for (int ks = 0; ks < 2; ++ks) {
      bf16x8 a[4], b[4];
#pragma unroll
      for (int t = 0; t < 4; ++t) {
        int ch = (ks * 4 + quad) ^ (mm & 7);
        a[t] = *(const bf16x8*)(As + (wm * 64 + t * 16 + mm) * 64 + ch * 8);
        b[t] = *(const bf16x8*)(Bs + (wn * 64 + t * 16 + mm) * 64 + ch * 8);
      }
#pragma unroll
      for (int i = 0; i < 4; ++i)
#pragma unroll
        for (int j = 0; j < 4; ++j) acc[i][j] = mfma16(a[i], b[j], acc[i][j]);
    }
    __syncthreads();
  }

  int sel = n0 >> 10;                                // uniform per block: 0=Q,1=K,2=V
  const float* bias = sel == 0 ? bq : (sel == 1 ? bk : bv);
  float scl = sel == 0 ? 0.125f : 1.0f;
#pragma unroll
  for (int j = 0; j < 4; ++j) {
    int ng = n0 + wn * 64 + j * 16 + mm;
    int h = (ng >> 6) & 15, d = ng & 63;
    float bval = bias[ng & 1023];
#pragma unroll
    for (int i = 0; i < 4; ++i)
#pragma unroll
      for (int r = 0; r < 4; ++r) {
        int mg = m0 + wm * 64 + i * 16 + quad * 4 + r;
        int b_ = mg >> 12, s = mg & 4095;
        float v = (acc[i][j][r] + bval) * scl;
        if (sel == 0)      Qb [((size_t)(b_ * 16 + h) * 4096 + s) * 64 + d] = f2bf(v);
        else if (sel == 1) Kb [((size_t)(b_ * 16 + h) * 4096 + s) * 64 + d] = f2bf(v);
        else               Vbt[((size_t)(b_ * 16 + h) * 64 + d) * 4096 + s] = f2bf(v);
      }
  }

  if (sel == 1) {
    // fold k_sumkey: sum over the 128 rows of this m-tile (one (b,n) exactly).
    float cs[4];
#pragma unroll
    for (int j = 0; j < 4; ++j) {
      int ng = n0 + wn * 64 + j * 16 + mm;
      float bval = bias[ng & 1023];
      float s = 16.f * bval;       // this thread covers 16 rows
#pragma unroll
      for (int i = 0; i < 4; ++i)
#pragma unroll
        for (int r = 0; r < 4; ++r) s += acc[i][j][r];
      s += __shfl_xor(s, 16);
      s += __shfl_xor(s, 32);      // reduce over quad -> sum of this wave's 64 rows
      cs[j] = s;
    }
    float* red = (float*)As;       // LDS free after final barrier
    if (quad == 0) {
#pragma unroll
      for (int j = 0; j < 4; ++j) red[wm * 128 + wn * 64 + j * 16 + mm] = cs[j];
    }
    __syncthreads();
    if (tid < 128) {
      int b_ = m0 >> 12, n = (m0 >> 7) & 31;
      sumk[(size_t)(b_ * 32 + n) * 1024 + (n0 - 1024) + tid] = red[tid] + red[128 + tid];
    }
  }
}

// ---------------- output GEMM (BK=64): X[16384x1024] * Wot[1024x1024]^T + bo -> fp32 ----------------
__global__ __launch_bounds__(256) void k_gemm_out(
    const u16* __restrict__ A, const u16* __restrict__ Bt,
    const float* __restrict__ bo, float* __restrict__ out)
{
  __shared__ u16 As[128 * 64];
  __shared__ u16 Bs[128 * 64];
  int tid = threadIdx.x, lane = tid & 63, w = tid >> 6;
  int wm = w >> 1, wn = w & 1;
  int m0 = blockIdx.y * 128, n0 = blockIdx.x * 128;
  int l8 = lane >> 3, sl8 = lane & 7;
  int pg = sl8 ^ l8;
  const u16* Ag[4]; const u16* Bg[4]; u16* La[4]; u16* Lb[4];
#pragma unroll
  for (int c = 0; c < 4; ++c) {
    int cc = w * 4 + c, row = cc * 8 + l8;
    Ag[c] = A + (size_t)(m0 + row) * 1024 + pg * 8;
    Bg[c] = Bt + (size_t)(n0 + row) * 1024 + pg * 8;
    La[c] = As + cc * 512;
    Lb[c] = Bs + cc * 512;
  }
  int mm = lane & 15, quad = lane >> 4;
  f32x4 acc[4][4];
#pragma unroll
  for (int i = 0; i < 4; ++i)
#pragma unroll
    for (int j = 0; j < 4; ++j) acc[i][j] = (f32x4){0.f, 0.f, 0.f, 0.f};
  for (int kt = 0; kt < 16; ++kt) {
    int ko = kt * 64;
#pragma unroll
    for (int c = 0; c < 4; ++c) { gll16(Ag[c] + ko, La[c]); gll16(Bg[c] + ko, Lb[c]); }
    __syncthreads();
#pragma unroll
    for (int ks = 0; ks < 2; ++ks) {
      bf16x8 a[4], b[4];
#pragma unroll
      for (int t = 0; t < 4; ++t) {
        int ch = (ks * 4 + quad) ^ (mm & 7);
        a[t] = *(const bf16x8*)(As + (wm * 64 + t * 16 + mm) * 64 + ch * 8);
        b[t] = *(const bf16x8*)(Bs + (wn * 64 + t * 16 + mm) * 64 + ch * 8);
      }
#pragma unroll
      for (int i = 0; i < 4; ++i)
#pragma unroll
        for (int j = 0; j < 4; ++j) acc[i][j] = mfma16(a[i], b[j], acc[i][j]);
    }
    __syncthreads();
  }
#pragma unroll
  for (int j = 0; j < 4; ++j) {
    int ng = n0 + wn * 64 + j * 16 + mm;
    float bval = bo[ng];
#pragma unroll
    for (int i = 0; i < 4; ++i)
#pragma unroll
      for (int r = 0; r < 4; ++r) {
        int mg = m0 + wm * 64 + i * 16 + quad * 4 + r;
        out[(size_t)mg * 1024 + ng] = acc[i][j][r] + bval;
      }
  }
}

// ---------------- sort logits: sumk[b][n][1024] @ w_sort[1024][32] + b_sort ----------------
__global__ __launch_bounds__(256) void k_sortmm(const float* __restrict__ sumk, const float* __restrict__ wsort,
                                                const float* __restrict__ bsort, float* __restrict__ so) {
  __shared__ float red[256];
  int n = blockIdx.x, b = blockIdx.y, t = threadIdx.x;
  int m = t & 31, kp = t >> 5;
  const float* row = sumk + (size_t)(b * 32 + n) * 1024;
  float acc = 0.f;
  for (int c = kp * 128; c < kp * 128 + 128; ++c) acc += row[c] * wsort[c * 32 + m];
  red[t] = acc;
  __syncthreads();
  if (t < 32) {
    float s = bsort[t];
#pragma unroll
    for (int q = 0; q < 8; ++q) s += red[q * 32 + t];
    so[(size_t)(b * 32 + n) * 32 + t] = s;
  }
}

// ---------------- Sinkhorn (5 iters) + clip + exp ----------------
__global__ __launch_bounds__(32) void k_sinkhorn(const float* __restrict__ so, float* __restrict__ perm) {
  __shared__ float A[32][33];
  int b = blockIdx.x, t = threadIdx.x;
  for (int i = 0; i < 32; ++i) A[i][t] = so[(size_t)(b * 32 + i) * 32 + t];
  __syncthreads();
  for (int it = 0; it < 5; ++it) {
    { // row LSE (axis=2)
      float mx = -1e30f;
      for (int j = 0; j < 32; ++j) mx = fmaxf(mx, A[t][j]);
      float s = 0.f;
      for (int j = 0; j < 32; ++j) s += __expf(A[t][j] - mx);
      float l = mx + __logf(s);
      for (int j = 0; j < 32; ++j) A[t][j] -= l;
    }
    __syncthreads();
    { // col LSE (axis=1)
      float mx = -1e30f;
      for (int j = 0; j < 32; ++j) mx = fmaxf(mx, A[j][t]);
      float s = 0.f;
      for (int j = 0; j < 32; ++j) s += __expf(A[j][t] - mx);
      float l = mx + __logf(s);
      for (int j = 0; j < 32; ++j) A[j][t] -= l;
    }
    __syncthreads();
  }
  for (int i = 0; i < 32; ++i)
    perm[(size_t)(b * 32 + i) * 32 + t] = __expf(fminf(fmaxf(A[i][t], -1.f), 1.f));
}

// ---------------- merged block mix: y<16 -> K-mix (h=y), y>=16 -> V-mix (h=y-16) ----------------
__global__ __launch_bounds__(256) void k_mix(
    const u16* __restrict__ Kb, const u16* __restrict__ Vbt, const float* __restrict__ perm,
    u16* __restrict__ Ksort, u16* __restrict__ Vsort)
{
  __shared__ float P[32][32];
  int b = blockIdx.z, y = blockIdx.y, xg = blockIdx.x;
  int tid = threadIdx.x;
#pragma unroll
  for (int i = 0; i < 4; ++i) {
    int idx = i * 256 + tid;
    P[idx >> 5][idx & 31] = perm[b * 1024 + idx];
  }
  __syncthreads();
  if (y < 16) {
    // K mix: Ksort[b][h][n][128s][64d] = sum_m perm[n][m] * K[b][h][m*128+s][d]
    int h = y;
    int ss = xg * 4 + (tid >> 6), d = tid & 63;
    const u16* Kg = Kb + (size_t)(b * 16 + h) * 262144;
    float xk[32];
#pragma unroll
    for (int m = 0; m < 32; ++m) xk[m] = bf2f(Kg[(size_t)(m * 128 + ss) * 64 + d]);
    size_t tbase = (size_t)((b * 16 + h) * 32) * 8192;
#pragma unroll
    for (int nn = 0; nn < 32; ++nn) {
      float sk = 0.f;
#pragma unroll
      for (int m4 = 0; m4 < 8; ++m4) {
        float4 pv = *(const float4*)&P[nn][m4 * 4];
        sk += pv.x * xk[m4 * 4 + 0] + pv.y * xk[m4 * 4 + 1] + pv.z * xk[m4 * 4 + 2] + pv.w * xk[m4 * 4 + 3];
      }
      Ksort[tbase + (size_t)nn * 8192 + ss * 64 + d] = f2bf(sk);
    }
  } else {
    // V mix (transposed): Vsort[b][h][n][64d][128s] from Vbt[b][h][d][s]
    int h = y - 16;
    int d = xg * 2 + (tid >> 7), ss = tid & 127;
    const u16* Vg = Vbt + ((size_t)(b * 16 + h) * 64 + d) * 4096;
    float xv[32];
#pragma unroll
    for (int m = 0; m < 32; ++m) xv[m] = bf2f(Vg[m * 128 + ss]);
    size_t tbase = (size_t)((b * 16 + h) * 32) * 8192;
#pragma unroll
    for (int nn = 0; nn < 32; ++nn) {
      float sv = 0.f;
#pragma unroll
      for (int m4 = 0; m4 < 8; ++m4) {
        float4 pv = *(const float4*)&P[nn][m4 * 4];
        sv += pv.x * xv[m4 * 4 + 0] + pv.y * xv[m4 * 4 + 1] + pv.z * xv[m4 * 4 + 2] + pv.w * xv[m4 * 4 + 3];
      }
      Vsort[tbase + (size_t)nn * 8192 + d * 128 + ss] = f2bf(sv);
    }
  }
}

// ---------------- attention per (b,n,h): softmax(Q Kcat^T) Vcat ----------------
__global__ __launch_bounds__(256, 2) void k_attn(
    const u16* __restrict__ Qb, const u16* __restrict__ Kb, const u16* __restrict__ Ksort,
    const u16* __restrict__ Vbt, const u16* __restrict__ Vsort, u16* __restrict__ X)
{
  __shared__ u16 Ks[16384];    // 256 kk x 64 d (swizzled); later overlaid by per-wave P
  __shared__ u16 Vlo[8192];    // 64 d x 128 kk (orig half, swizzled)
  __shared__ u16 Vhi[8192];    // 64 d x 128 kk (sorted half, swizzled)
  int tid = threadIdx.x, lane = tid & 63, w = tid >> 6;
  int n = blockIdx.x, h = blockIdx.y, b = blockIdx.z;
  size_t bh = (size_t)(b * 16 + h);
  size_t tileK = bh * 32 + n;

  { // stage Kcat rows: [0,128) from Kb, [128,256) from Ksort. chunk = 8 rows x 64 u16.
    int l8 = lane >> 3, sl8 = lane & 7;
    const u16* Korig = Kb + (bh * 4096 + (size_t)n * 128) * 64;
    const u16* Ksrt  = Ksort + tileK * 8192;
#pragma unroll
    for (int c = 0; c < 8; ++c) {
      int cc = w * 8 + c;
      int r = cc * 8 + l8;
      int pk = sl8 ^ (r & 7);
      const u16* src = (cc < 16) ? (Korig + (size_t)r * 64 + pk * 8)
                                 : (Ksrt + (size_t)(r - 128) * 64 + pk * 8);
      gll16(src, Ks + cc * 512);
    }
    // stage V panels: chunk = 4 d-rows x 128 u16.
    int l16 = lane >> 4, sl16 = lane & 15;
    const u16* Vorig = Vbt + bh * 262144 + (size_t)n * 128;
    const u16* Vsrt  = Vsort + tileK * 8192;
#pragma unroll
    for (int c = 0; c < 4; ++c) {
      int cc = w * 4 + c;
      int d = cc * 4 + l16;
      int pv = sl16 ^ (d & 15);
      gll16(Vorig + (size_t)d * 4096 + pv * 8, Vlo + cc * 512);
      gll16(Vsrt + (size_t)d * 128 + pv * 8, Vhi + cc * 512);
    }
  }

  int mm = lane & 15, quad = lane >> 4;
  bf16x8 qf[2][2];
  {
    size_t qrow = bh * 4096 + n * 128 + w * 32;
#pragma unroll
    for (int mt = 0; mt < 2; ++mt)
#pragma unroll
      for (int ks = 0; ks < 2; ++ks)
        qf[mt][ks] = *(const bf16x8*)(Qb + (qrow + mt * 16 + mm) * 64 + ks * 32 + quad * 8);
  }
  __syncthreads();

  // S = Qs @ Kcat^T  (wave w owns q rows [w*32, w*32+32))
  f32x4 S[2][16];
#pragma unroll
  for (int mt = 0; mt < 2; ++mt)
#pragma unroll
    for (int nt = 0; nt < 16; ++nt) S[mt][nt] = (f32x4){0.f, 0.f, 0.f, 0.f};
#pragma unroll
  for (int nt = 0; nt < 16; ++nt) {
    int kk = nt * 16 + mm;
#pragma unroll
    for (int ks = 0; ks < 2; ++ks) {
      int ch = (ks * 4 + quad) ^ (kk & 7);
      bf16x8 bk = *(const bf16x8*)(Ks + kk * 64 + ch * 8);
      S[0][nt] = mfma16(qf[0][ks], bk, S[0][nt]);
      S[1][nt] = mfma16(qf[1][ks], bk, S[1][nt]);
    }
  }

  // softmax over kk (C-layout: row = quad*4+r, col = mm across nt)
  float mx[2][4], ls[2][4];
#pragma unroll
  for (int mt = 0; mt < 2; ++mt)
#pragma unroll
    for (int r = 0; r < 4; ++r) {
      float v = S[mt][0][r];
#pragma unroll
      for (int nt = 1; nt < 16; ++nt) v = fmaxf(v, S[mt][nt][r]);
#pragma unroll
      for (int o = 1; o < 16; o <<= 1) v = fmaxf(v, __shfl_xor(v, o));
      mx[mt][r] = v;
    }
#pragma unroll
  for (int mt = 0; mt < 2; ++mt)
#pragma unroll
    for (int nt = 0; nt < 16; ++nt)
#pragma unroll
      for (int r = 0; r < 4; ++r)
        S[mt][nt][r] = __expf(S[mt][nt][r] - mx[mt][r]);
#pragma unroll
  for (int mt = 0; mt < 2; ++mt)
#pragma unroll
    for (int r = 0; r < 4; ++r) {
      float s = 0.f;
#pragma unroll
      for (int nt = 0; nt < 16; ++nt) s += S[mt][nt][r];
#pragma unroll
      for (int o = 1; o < 16; o <<= 1) s += __shfl_xor(s, o);
      ls[mt][r] = s;
    }

  __syncthreads();   // all waves done reading Ks before overlaying with P

  // PV in two kk halves; P (bf16) round-trips through per-wave LDS region over Ks
  u16* Pw = Ks + w * 4096;   // 32 q-rows x 128 kk per half (8KB per wave)
  f32x4 O[2][4];
#pragma unroll
  for (int mt = 0; mt < 2; ++mt)
#pragma unroll
    for (int dt = 0; dt < 4; ++dt) O[mt][dt] = (f32x4){0.f, 0.f, 0.f, 0.f};

#pragma unroll
  for (int half = 0; half < 2; ++half) {
    const u16* Vp = half == 0 ? Vlo : Vhi;
#pragma unroll
    for (int mt = 0; mt < 2; ++mt)
#pragma unroll
      for (int nt8 = 0; nt8 < 8; ++nt8) {
        int nt = half * 8 + nt8;
        int kkl = nt8 * 16 + mm;
#pragma unroll
        for (int r = 0; r < 4; ++r) {
          int q = mt * 16 + quad * 4 + r;
          int ch = (kkl >> 3) ^ (q & 15);
          Pw[q * 128 + ch * 8 + (kkl & 7)] = f2bf(S[mt][nt][r]);
        }
      }
#pragma unroll
    for (int ksl = 0; ksl < 4; ++ksl) {
      bf16x8 pa[2];
#pragma unroll
      for (int mt = 0; mt < 2; ++mt) {
        int q = mt * 16 + mm;
        int ch = (ksl * 4 + quad) ^ (q & 15);
        pa[mt] = *(const bf16x8*)(Pw + q * 128 + ch * 8);
      }
#pragma unroll
      for (int dt = 0; dt < 4; ++dt) {
        int d = dt * 16 + mm;
        int ch = (ksl * 4 + quad) ^ (d & 15);
        bf16x8 vb = *(const bf16x8*)(Vp + d * 128 + ch * 8);
        O[0][dt] = mfma16(pa[0], vb, O[0][dt]);
        O[1][dt] = mfma16(pa[1], vb, O[1][dt]);
      }
    }
  }

  // epilogue: normalize and write X[b*4096+s][h*64+d] (bf16)
#pragma unroll
  for (int mt = 0; mt < 2; ++mt)
#pragma unroll
    for (int dt = 0; dt < 4; ++dt)
#pragma unroll
      for (int r = 0; r < 4; ++r) {
        int q = w * 32 + mt * 16 + quad * 4 + r;
        float val = O[mt][dt][r] / ls[mt][r];
        size_t row = (size_t)b * 4096 + n * 128 + q;
        X[row * 1024 + h * 64 + dt * 16 + mm] = f2bf(val);
      }
}

// ---------------- launch ----------------
extern "C" void kernel_launch(void* const* d_in, const int* in_sizes, int n_in,
                              void* d_out, int out_size, void* d_ws, size_t ws_size,
                              hipStream_t stream) {
  const float* inq   = (const float*)d_in[0];
  const float* wq    = (const float*)d_in[1];
  const float* bq    = (const float*)d_in[2];
  const float* wk    = (const float*)d_in[3];
  const float* bk    = (const float*)d_in[4];
  const float* wv    = (const float*)d_in[5];
  const float* bv    = (const float*)d_in[6];
  const float* wsort = (const float*)d_in[7];
  const float* bsort = (const float*)d_in[8];
  const float* wo    = (const float*)d_in[9];
  const float* bo    = (const float*)d_in[10];
  float* out = (float*)d_out;

  char* ws = (char*)d_ws;
  size_t off = 0;
  auto alloc = [&](size_t bytes) { char* p = ws + off; off += (bytes + 255) & ~(size_t)255; return p; };
  u16*  Qb    = (u16*)alloc(33554432);   // [4][16][4096][64] bf16, pre-scaled 1/8
  u16*  Kb    = (u16*)alloc(33554432);   // K [4][16][4096][64]
  u16*  Vbt   = (u16*)alloc(33554432);   // V transposed [4][16][64][4096]
  u16*  Ksort = (u16*)alloc(33554432);   // sorted K [4][16][32][128][64]
  u16*  Vsort = (u16*)alloc(33554432);   // sorted V^T [4][16][32][64][128]
  u16*  Abf   = (u16*)alloc(33554432);   // bf16 input; later aliased as X
  u16*  Wqkvt = (u16*)alloc(6291456);    // [3072][1024] bf16 (B^T)
  u16*  Wot   = (u16*)alloc(2097152);    // [1024][1024] bf16 (B^T)
  float* sumk = (float*)alloc(524288);   // [4][32][1024]
  float* so   = (float*)alloc(16384);    // [4][32][32]
  float* perm = (float*)alloc(16384);    // [4][32][32]
  u16*  X = Abf;   // alias: attention output over Abf (dead after k_gemm_qkv)

  k_cast<<<16384, 256, 0, stream>>>(inq, Abf);
  k_transpose4<<<dim3(32, 32, 4), dim3(32, 32), 0, stream>>>(wq, wk, wv, wo, Wqkvt, Wot);
  k_gemm_qkv<<<dim3(24, 128), 256, 0, stream>>>(Abf, Wqkvt, bq, bk, bv, Qb, Kb, Vbt, sumk);
  k_sortmm<<<dim3(32, 4), 256, 0, stream>>>(sumk, wsort, bsort, so);
  k_sinkhorn<<<4, 32, 0, stream>>>(so, perm);
  k_mix<<<dim3(32, 32, 4), 256, 0, stream>>>(Kb, Vbt, perm, Ksort, Vsort);
  k_attn<<<dim3(32, 16, 4), 256, 0, stream>>>(Qb, Kb, Ksort, Vbt, Vsort, X);
  k_gemm_out<<<dim3(8, 128), 256, 0, stream>>>(X, Wot, bo, out);
}

// Round 4
// 500.341 us; speedup vs baseline: 1.0470x; 1.0031x over previous
//
#include <hip/hip_runtime.h>
#include <stdint.h>

// ---------------- types / helpers ----------------
typedef short bf16x8 __attribute__((ext_vector_type(8)));
typedef float f32x4 __attribute__((ext_vector_type(4)));
typedef unsigned short u16;
typedef unsigned short u16x4 __attribute__((ext_vector_type(4)));

#define AS1 __attribute__((address_space(1)))
#define AS3 __attribute__((address_space(3)))

__device__ __forceinline__ void gll16(const void* g, void* l) {
  // async global->LDS, 16B per lane, LDS dest = wave-uniform base + lane*16
  __builtin_amdgcn_global_load_lds((const AS1 uint32_t*)g, (AS3 uint32_t*)l, 16, 0, 0);
}

__device__ __forceinline__ f32x4 mfma16(bf16x8 a, bf16x8 b, f32x4 c) {
  return __builtin_amdgcn_mfma_f32_16x16x32_bf16(a, b, c, 0, 0, 0);
}

__device__ __forceinline__ u16 f2bf(float f) {
  union { float f; uint32_t u; } c; c.f = f;
  uint32_t r = c.u + 0x7FFFu + ((c.u >> 16) & 1u);   // RNE
  return (u16)(r >> 16);
}
__device__ __forceinline__ float bf2f(u16 h) {
  union { uint32_t u; float f; } c; c.u = ((uint32_t)h) << 16; return c.f;
}

// ---------------- cast fp32 -> bf16 ----------------
__global__ __launch_bounds__(256) void k_cast(const float* __restrict__ in, u16* __restrict__ out) {
  int i = (blockIdx.x * 256 + threadIdx.x) * 4;
  float4 v = *(const float4*)(in + i);
  u16x4 r; r.x = f2bf(v.x); r.y = f2bf(v.y); r.z = f2bf(v.z); r.w = f2bf(v.w);
  *(u16x4*)(out + i) = r;
}

// ---------------- 4 weight transposes fp32 (1024x1024) -> bf16 transposed, one dispatch ----------------
__global__ __launch_bounds__(1024) void k_transpose4(
    const float* __restrict__ wq, const float* __restrict__ wk,
    const float* __restrict__ wv, const float* __restrict__ wo,
    u16* __restrict__ Wqkvt, u16* __restrict__ Wot) {
  __shared__ float t[32][33];
  const float* src; u16* dst;
  int z = blockIdx.z;
  if (z == 0)      { src = wq; dst = Wqkvt; }
  else if (z == 1) { src = wk; dst = Wqkvt + 1024 * 1024; }
  else if (z == 2) { src = wv; dst = Wqkvt + 2 * 1024 * 1024; }
  else             { src = wo; dst = Wot; }
  int tx = threadIdx.x, ty = threadIdx.y;
  t[ty][tx] = src[(size_t)(blockIdx.y * 32 + ty) * 1024 + blockIdx.x * 32 + tx];
  __syncthreads();
  dst[(size_t)(blockIdx.x * 32 + ty) * 1024 + blockIdx.y * 32 + tx] = f2bf(t[tx][ty]);
}

// ---------------- fused QKV GEMM (BK=32): A[16384x1024] * Wt[3072x1024]^T ----------------
// Q (scaled 1/8) -> [b][h][s][d]; K -> [b][h][s][d]; V -> TRANSPOSED [b][h][d][s]
// K-blocks also emit per-block key sums (sumk) from fp32 accumulators.
// __launch_bounds__(256,4): target 4 waves/SIMD (64 VGPR + 64 AGPR = 128 unified regs)
__global__ __launch_bounds__(256, 4) void k_gemm_qkv(
    const u16* __restrict__ A, const u16* __restrict__ Bt,
    const float* __restrict__ bq, const float* __restrict__ bk, const float* __restrict__ bv,
    u16* __restrict__ Qb, u16* __restrict__ Kb, u16* __restrict__ Vbt, float* __restrict__ sumk)
{
  __shared__ u16 As[128 * 32];   // 8 KB
  __shared__ u16 Bs[128 * 32];   // 8 KB
  int tid = threadIdx.x, lane = tid & 63, w = tid >> 6;
  int wm = w >> 1, wn = w & 1;
  int m0 = blockIdx.y * 128, n0 = blockIdx.x * 128;

  // staging: wave w stages chunks {2w,2w+1} of A and B. chunk = 16 rows x 32 k.
  int l4 = lane >> 2;
  int p = (lane & 3) ^ ((lane >> 3) & 3);          // swizzled global k-chunk (8 elems)
  const u16* Ag0 = A + (size_t)(m0 + w * 32 + l4) * 1024 + p * 8;
  const u16* Ag1 = A + (size_t)(m0 + w * 32 + 16 + l4) * 1024 + p * 8;
  const u16* Bg0 = Bt + (size_t)(n0 + w * 32 + l4) * 1024 + p * 8;
  const u16* Bg1 = Bt + (size_t)(n0 + w * 32 + 16 + l4) * 1024 + p * 8;
  u16* La0 = As + w * 1024; u16* La1 = As + w * 1024 + 512;
  u16* Lb0 = Bs + w * 1024; u16* Lb1 = Bs + w * 1024 + 512;

  int mm = lane & 15, quad = lane >> 4;
  int sw = quad ^ ((mm >> 1) & 3);                  // swizzled LDS chunk for frag reads
  const bf16x8* pa[4]; const bf16x8* pb[4];
#pragma unroll
  for (int t = 0; t < 4; ++t) {
    pa[t] = (const bf16x8*)(As + (wm * 64 + t * 16 + mm) * 32 + sw * 8);
    pb[t] = (const bf16x8*)(Bs + (wn * 64 + t * 16 + mm) * 32 + sw * 8);
  }

  f32x4 acc[4][4];
#pragma unroll
  for (int i = 0; i < 4; ++i)
#pragma unroll
    for (int j = 0; j < 4; ++j) acc[i][j] = (f32x4){0.f, 0.f, 0.f, 0.f};

  for (int kt = 0; kt < 32; ++kt) {
    int ko = kt * 32;
    gll16(Ag0 + ko, La0); gll16(Ag1 + ko, La1);
    gll16(Bg0 + ko, Lb0); gll16(Bg1 + ko, Lb1);
    __syncthreads();
    bf16x8 a[4], b[4];
#pragma unroll
    for (int t = 0; t < 4; ++t) { a[t] = *pa[t]; b[t] = *pb[t]; }
#pragma unroll
    for (int i = 0; i < 4; ++i)
#pragma unroll
      for (int j = 0; j < 4; ++j) acc[i][j] = mfma16(a[i], b[j], acc[i][j]);
    __syncthreads();
  }

  int sel = n0 >> 10;                                // uniform per block: 0=Q,1=K,2=V
  const float* bias = sel == 0 ? bq : (sel == 1 ? bk : bv);
  float scl = sel == 0 ? 0.125f : 1.0f;
#pragma unroll
  for (int j = 0; j < 4; ++j) {
    int ng = n0 + wn * 64 + j * 16 + mm;
    int h = (ng >> 6) & 15, d = ng & 63;
    float bval = bias[ng & 1023];
#pragma unroll
    for (int i = 0; i < 4; ++i)
#pragma unroll
      for (int r = 0; r < 4; ++r) {
        int mg = m0 + wm * 64 + i * 16 + quad * 4 + r;
        int b_ = mg >> 12, s = mg & 4095;
        float v = (acc[i][j][r] + bval) * scl;
        if (sel == 0)      Qb [((size_t)(b_ * 16 + h) * 4096 + s) * 64 + d] = f2bf(v);
        else if (sel == 1) Kb [((size_t)(b_ * 16 + h) * 4096 + s) * 64 + d] = f2bf(v);
        else               Vbt[((size_t)(b_ * 16 + h) * 64 + d) * 4096 + s] = f2bf(v);
      }
  }

  if (sel == 1) {
    // fold k_sumkey: sum over the 128 rows of this m-tile (one (b,n) exactly).
    float cs[4];
#pragma unroll
    for (int j = 0; j < 4; ++j) {
      int ng = n0 + wn * 64 + j * 16 + mm;
      float bval = bias[ng & 1023];
      float s = 16.f * bval;       // this thread covers 16 rows
#pragma unroll
      for (int i = 0; i < 4; ++i)
#pragma unroll
        for (int r = 0; r < 4; ++r) s += acc[i][j][r];
      s += __shfl_xor(s, 16);
      s += __shfl_xor(s, 32);      // reduce over quad -> sum of this wave's 64 rows
      cs[j] = s;
    }
    float* red = (float*)As;       // LDS free after final barrier
    if (quad == 0) {
#pragma unroll
      for (int j = 0; j < 4; ++j) red[wm * 128 + wn * 64 + j * 16 + mm] = cs[j];
    }
    __syncthreads();
    if (tid < 128) {
      int b_ = m0 >> 12, n = (m0 >> 7) & 31;
      sumk[(size_t)(b_ * 32 + n) * 1024 + (n0 - 1024) + tid] = red[tid] + red[128 + tid];
    }
  }
}

// ---------------- output GEMM (BK=32): X[16384x1024] * Wot[1024x1024]^T + bo -> fp32 ----------------
__global__ __launch_bounds__(256, 4) void k_gemm_out(
    const u16* __restrict__ A, const u16* __restrict__ Bt,
    const float* __restrict__ bo, float* __restrict__ out)
{
  __shared__ u16 As[128 * 32];
  __shared__ u16 Bs[128 * 32];
  int tid = threadIdx.x, lane = tid & 63, w = tid >> 6;
  int wm = w >> 1, wn = w & 1;
  int m0 = blockIdx.y * 128, n0 = blockIdx.x * 128;
  int l4 = lane >> 2;
  int p = (lane & 3) ^ ((lane >> 3) & 3);
  const u16* Ag0 = A + (size_t)(m0 + w * 32 + l4) * 1024 + p * 8;
  const u16* Ag1 = A + (size_t)(m0 + w * 32 + 16 + l4) * 1024 + p * 8;
  const u16* Bg0 = Bt + (size_t)(n0 + w * 32 + l4) * 1024 + p * 8;
  const u16* Bg1 = Bt + (size_t)(n0 + w * 32 + 16 + l4) * 1024 + p * 8;
  u16* La0 = As + w * 1024; u16* La1 = As + w * 1024 + 512;
  u16* Lb0 = Bs + w * 1024; u16* Lb1 = Bs + w * 1024 + 512;
  int mm = lane & 15, quad = lane >> 4;
  int sw = quad ^ ((mm >> 1) & 3);
  const bf16x8* pa[4]; const bf16x8* pb[4];
#pragma unroll
  for (int t = 0; t < 4; ++t) {
    pa[t] = (const bf16x8*)(As + (wm * 64 + t * 16 + mm) * 32 + sw * 8);
    pb[t] = (const bf16x8*)(Bs + (wn * 64 + t * 16 + mm) * 32 + sw * 8);
  }
  f32x4 acc[4][4];
#pragma unroll
  for (int i = 0; i < 4; ++i)
#pragma unroll
    for (int j = 0; j < 4; ++j) acc[i][j] = (f32x4){0.f, 0.f, 0.f, 0.f};
  for (int kt = 0; kt < 32; ++kt) {
    int ko = kt * 32;
    gll16(Ag0 + ko, La0); gll16(Ag1 + ko, La1);
    gll16(Bg0 + ko, Lb0); gll16(Bg1 + ko, Lb1);
    __syncthreads();
    bf16x8 a[4], b[4];
#pragma unroll
    for (int t = 0; t < 4; ++t) { a[t] = *pa[t]; b[t] = *pb[t]; }
#pragma unroll
    for (int i = 0; i < 4; ++i)
#pragma unroll
      for (int j = 0; j < 4; ++j) acc[i][j] = mfma16(a[i], b[j], acc[i][j]);
    __syncthreads();
  }
#pragma unroll
  for (int j = 0; j < 4; ++j) {
    int ng = n0 + wn * 64 + j * 16 + mm;
    float bval = bo[ng];
#pragma unroll
    for (int i = 0; i < 4; ++i)
#pragma unroll
      for (int r = 0; r < 4; ++r) {
        int mg = m0 + wm * 64 + i * 16 + quad * 4 + r;
        out[(size_t)mg * 1024 + ng] = acc[i][j][r] + bval;
      }
  }
}

// ---------------- sort logits: sumk[b][n][1024] @ w_sort[1024][32] + b_sort ----------------
__global__ __launch_bounds__(256) void k_sortmm(const float* __restrict__ sumk, const float* __restrict__ wsort,
                                                const float* __restrict__ bsort, float* __restrict__ so) {
  __shared__ float red[256];
  int n = blockIdx.x, b = blockIdx.y, t = threadIdx.x;
  int m = t & 31, kp = t >> 5;
  const float* row = sumk + (size_t)(b * 32 + n) * 1024;
  float acc = 0.f;
  for (int c = kp * 128; c < kp * 128 + 128; ++c) acc += row[c] * wsort[c * 32 + m];
  red[t] = acc;
  __syncthreads();
  if (t < 32) {
    float s = bsort[t];
#pragma unroll
    for (int q = 0; q < 8; ++q) s += red[q * 32 + t];
    so[(size_t)(b * 32 + n) * 32 + t] = s;
  }
}

// ---------------- Sinkhorn (5 iters) + clip + exp ----------------
__global__ __launch_bounds__(32) void k_sinkhorn(const float* __restrict__ so, float* __restrict__ perm) {
  __shared__ float A[32][33];
  int b = blockIdx.x, t = threadIdx.x;
  for (int i = 0; i < 32; ++i) A[i][t] = so[(size_t)(b * 32 + i) * 32 + t];
  __syncthreads();
  for (int it = 0; it < 5; ++it) {
    { // row LSE (axis=2)
      float mx = -1e30f;
      for (int j = 0; j < 32; ++j) mx = fmaxf(mx, A[t][j]);
      float s = 0.f;
      for (int j = 0; j < 32; ++j) s += __expf(A[t][j] - mx);
      float l = mx + __logf(s);
      for (int j = 0; j < 32; ++j) A[t][j] -= l;
    }
    __syncthreads();
    { // col LSE (axis=1)
      float mx = -1e30f;
      for (int j = 0; j < 32; ++j) mx = fmaxf(mx, A[j][t]);
      float s = 0.f;
      for (int j = 0; j < 32; ++j) s += __expf(A[j][t] - mx);
      float l = mx + __logf(s);
      for (int j = 0; j < 32; ++j) A[j][t] -= l;
    }
    __syncthreads();
  }
  for (int i = 0; i < 32; ++i)
    perm[(size_t)(b * 32 + i) * 32 + t] = __expf(fminf(fmaxf(A[i][t], -1.f), 1.f));
}

// ---------------- merged block mix: y<16 -> K-mix (h=y), y>=16 -> V-mix (h=y-16) ----------------
__global__ __launch_bounds__(256) void k_mix(
    const u16* __restrict__ Kb, const u16* __restrict__ Vbt, const float* __restrict__ perm,
    u16* __restrict__ Ksort, u16* __restrict__ Vsort)
{
  __shared__ float P[32][32];
  int b = blockIdx.z, y = blockIdx.y, xg = blockIdx.x;
  int tid = threadIdx.x;
#pragma unroll
  for (int i = 0; i < 4; ++i) {
    int idx = i * 256 + tid;
    P[idx >> 5][idx & 31] = perm[b * 1024 + idx];
  }
  __syncthreads();
  if (y < 16) {
    // K mix: Ksort[b][h][n][128s][64d] = sum_m perm[n][m] * K[b][h][m*128+s][d]
    int h = y;
    int ss = xg * 4 + (tid >> 6), d = tid & 63;
    const u16* Kg = Kb + (size_t)(b * 16 + h) * 262144;
    float xk[32];
#pragma unroll
    for (int m = 0; m < 32; ++m) xk[m] = bf2f(Kg[(size_t)(m * 128 + ss) * 64 + d]);
    size_t tbase = (size_t)((b * 16 + h) * 32) * 8192;
#pragma unroll
    for (int nn = 0; nn < 32; ++nn) {
      float sk = 0.f;
#pragma unroll
      for (int m4 = 0; m4 < 8; ++m4) {
        float4 pv = *(const float4*)&P[nn][m4 * 4];
        sk += pv.x * xk[m4 * 4 + 0] + pv.y * xk[m4 * 4 + 1] + pv.z * xk[m4 * 4 + 2] + pv.w * xk[m4 * 4 + 3];
      }
      Ksort[tbase + (size_t)nn * 8192 + ss * 64 + d] = f2bf(sk);
    }
  } else {
    // V mix (transposed): Vsort[b][h][n][64d][128s] from Vbt[b][h][d][s]
    int h = y - 16;
    int d = xg * 2 + (tid >> 7), ss = tid & 127;
    const u16* Vg = Vbt + ((size_t)(b * 16 + h) * 64 + d) * 4096;
    float xv[32];
#pragma unroll
    for (int m = 0; m < 32; ++m) xv[m] = bf2f(Vg[m * 128 + ss]);
    size_t tbase = (size_t)((b * 16 + h) * 32) * 8192;
#pragma unroll
    for (int nn = 0; nn < 32; ++nn) {
      float sv = 0.f;
#pragma unroll
      for (int m4 = 0; m4 < 8; ++m4) {
        float4 pv = *(const float4*)&P[nn][m4 * 4];
        sv += pv.x * xv[m4 * 4 + 0] + pv.y * xv[m4 * 4 + 1] + pv.z * xv[m4 * 4 + 2] + pv.w * xv[m4 * 4 + 3];
      }
      Vsort[tbase + (size_t)nn * 8192 + d * 128 + ss] = f2bf(sv);
    }
  }
}

// ---------------- attention per (b,n,h): softmax(Q Kcat^T) Vcat ----------------
__global__ __launch_bounds__(256, 2) void k_attn(
    const u16* __restrict__ Qb, const u16* __restrict__ Kb, const u16* __restrict__ Ksort,
    const u16* __restrict__ Vbt, const u16* __restrict__ Vsort, u16* __restrict__ X)
{
  __shared__ u16 Ks[16384];    // 256 kk x 64 d (swizzled); later overlaid by per-wave P
  __shared__ u16 Vlo[8192];    // 64 d x 128 kk (orig half, swizzled)
  __shared__ u16 Vhi[8192];    // 64 d x 128 kk (sorted half, swizzled)
  int tid = threadIdx.x, lane = tid & 63, w = tid >> 6;
  int n = blockIdx.x, h = blockIdx.y, b = blockIdx.z;
  size_t bh = (size_t)(b * 16 + h);
  size_t tileK = bh * 32 + n;

  { // stage Kcat rows: [0,128) from Kb, [128,256) from Ksort. chunk = 8 rows x 64 u16.
    int l8 = lane >> 3, sl8 = lane & 7;
    const u16* Korig = Kb + (bh * 4096 + (size_t)n * 128) * 64;
    const u16* Ksrt  = Ksort + tileK * 8192;
#pragma unroll
    for (int c = 0; c < 8; ++c) {
      int cc = w * 8 + c;
      int r = cc * 8 + l8;
      int pk = sl8 ^ (r & 7);
      const u16* src = (cc < 16) ? (Korig + (size_t)r * 64 + pk * 8)
                                 : (Ksrt + (size_t)(r - 128) * 64 + pk * 8);
      gll16(src, Ks + cc * 512);
    }
    // stage V panels: chunk = 4 d-rows x 128 u16.
    int l16 = lane >> 4, sl16 = lane & 15;
    const u16* Vorig = Vbt + bh * 262144 + (size_t)n * 128;
    const u16* Vsrt  = Vsort + tileK * 8192;
#pragma unroll
    for (int c = 0; c < 4; ++c) {
      int cc = w * 4 + c;
      int d = cc * 4 + l16;
      int pv = sl16 ^ (d & 15);
      gll16(Vorig + (size_t)d * 4096 + pv * 8, Vlo + cc * 512);
      gll16(Vsrt + (size_t)d * 128 + pv * 8, Vhi + cc * 512);
    }
  }

  int mm = lane & 15, quad = lane >> 4;
  bf16x8 qf[2][2];
  {
    size_t qrow = bh * 4096 + n * 128 + w * 32;
#pragma unroll
    for (int mt = 0; mt < 2; ++mt)
#pragma unroll
      for (int ks = 0; ks < 2; ++ks)
        qf[mt][ks] = *(const bf16x8*)(Qb + (qrow + mt * 16 + mm) * 64 + ks * 32 + quad * 8);
  }
  __syncthreads();

  // S = Qs @ Kcat^T  (wave w owns q rows [w*32, w*32+32))
  f32x4 S[2][16];
#pragma unroll
  for (int mt = 0; mt < 2; ++mt)
#pragma unroll
    for (int nt = 0; nt < 16; ++nt) S[mt][nt] = (f32x4){0.f, 0.f, 0.f, 0.f};
#pragma unroll
  for (int nt = 0; nt < 16; ++nt) {
    int kk = nt * 16 + mm;
#pragma unroll
    for (int ks = 0; ks < 2; ++ks) {
      int ch = (ks * 4 + quad) ^ (kk & 7);
      bf16x8 bk = *(const bf16x8*)(Ks + kk * 64 + ch * 8);
      S[0][nt] = mfma16(qf[0][ks], bk, S[0][nt]);
      S[1][nt] = mfma16(qf[1][ks], bk, S[1][nt]);
    }
  }

  // softmax over kk (C-layout: row = quad*4+r, col = mm across nt)
  float mx[2][4], ls[2][4];
#pragma unroll
  for (int mt = 0; mt < 2; ++mt)
#pragma unroll
    for (int r = 0; r < 4; ++r) {
      float v = S[mt][0][r];
#pragma unroll
      for (int nt = 1; nt < 16; ++nt) v = fmaxf(v, S[mt][nt][r]);
#pragma unroll
      for (int o = 1; o < 16; o <<= 1) v = fmaxf(v, __shfl_xor(v, o));
      mx[mt][r] = v;
    }
#pragma unroll
  for (int mt = 0; mt < 2; ++mt)
#pragma unroll
    for (int nt = 0; nt < 16; ++nt)
#pragma unroll
      for (int r = 0; r < 4; ++r)
        S[mt][nt][r] = __expf(S[mt][nt][r] - mx[mt][r]);
#pragma unroll
  for (int mt = 0; mt < 2; ++mt)
#pragma unroll
    for (int r = 0; r < 4; ++r) {
      float s = 0.f;
#pragma unroll
      for (int nt = 0; nt < 16; ++nt) s += S[mt][nt][r];
#pragma unroll
      for (int o = 1; o < 16; o <<= 1) s += __shfl_xor(s, o);
      ls[mt][r] = s;
    }

  __syncthreads();   // all waves done reading Ks before overlaying with P

  // PV in two kk halves; P (bf16) round-trips through per-wave LDS region over Ks
  u16* Pw = Ks + w * 4096;   // 32 q-rows x 128 kk per half (8KB per wave)
  f32x4 O[2][4];
#pragma unroll
  for (int mt = 0; mt < 2; ++mt)
#pragma unroll
    for (int dt = 0; dt < 4; ++dt) O[mt][dt] = (f32x4){0.f, 0.f, 0.f, 0.f};

#pragma unroll
  for (int half = 0; half < 2; ++half) {
    const u16* Vp = half == 0 ? Vlo : Vhi;
#pragma unroll
    for (int mt = 0; mt < 2; ++mt)
#pragma unroll
      for (int nt8 = 0; nt8 < 8; ++nt8) {
        int nt = half * 8 + nt8;
        int kkl = nt8 * 16 + mm;
#pragma unroll
        for (int r = 0; r < 4; ++r) {
          int q = mt * 16 + quad * 4 + r;
          int ch = (kkl >> 3) ^ (q & 15);
          Pw[q * 128 + ch * 8 + (kkl & 7)] = f2bf(S[mt][nt][r]);
        }
      }
#pragma unroll
    for (int ksl = 0; ksl < 4; ++ksl) {
      bf16x8 pa[2];
#pragma unroll
      for (int mt = 0; mt < 2; ++mt) {
        int q = mt * 16 + mm;
        int ch = (ksl * 4 + quad) ^ (q & 15);
        pa[mt] = *(const bf16x8*)(Pw + q * 128 + ch * 8);
      }
#pragma unroll
      for (int dt = 0; dt < 4; ++dt) {
        int d = dt * 16 + mm;
        int ch = (ksl * 4 + quad) ^ (d & 15);
        bf16x8 vb = *(const bf16x8*)(Vp + d * 128 + ch * 8);
        O[0][dt] = mfma16(pa[0], vb, O[0][dt]);
        O[1][dt] = mfma16(pa[1], vb, O[1][dt]);
      }
    }
  }

  // epilogue: normalize and write X[b*4096+s][h*64+d] (bf16)
#pragma unroll
  for (int mt = 0; mt < 2; ++mt)
#pragma unroll
    for (int dt = 0; dt < 4; ++dt)
#pragma unroll
      for (int r = 0; r < 4; ++r) {
        int q = w * 32 + mt * 16 + quad * 4 + r;
        float val = O[mt][dt][r] / ls[mt][r];
        size_t row = (size_t)b * 4096 + n * 128 + q;
        X[row * 1024 + h * 64 + dt * 16 + mm] = f2bf(val);
      }
}

// ---------------- launch ----------------
extern "C" void kernel_launch(void* const* d_in, const int* in_sizes, int n_in,
                              void* d_out, int out_size, void* d_ws, size_t ws_size,
                              hipStream_t stream) {
  const float* inq   = (const float*)d_in[0];
  const float* wq    = (const float*)d_in[1];
  const float* bq    = (const float*)d_in[2];
  const float* wk    = (const float*)d_in[3];
  const float* bk    = (const float*)d_in[4];
  const float* wv    = (const float*)d_in[5];
  const float* bv    = (const float*)d_in[6];
  const float* wsort = (const float*)d_in[7];
  const float* bsort = (const float*)d_in[8];
  const float* wo    = (const float*)d_in[9];
  const float* bo    = (const float*)d_in[10];
  float* out = (float*)d_out;

  char* ws = (char*)d_ws;
  size_t off = 0;
  auto alloc = [&](size_t bytes) { char* p = ws + off; off += (bytes + 255) & ~(size_t)255; return p; };
  u16*  Qb    = (u16*)alloc(33554432);   // [4][16][4096][64] bf16, pre-scaled 1/8
  u16*  Kb    = (u16*)alloc(33554432);   // K [4][16][4096][64]
  u16*  Vbt   = (u16*)alloc(33554432);   // V transposed [4][16][64][4096]
  u16*  Ksort = (u16*)alloc(33554432);   // sorted K [4][16][32][128][64]
  u16*  Vsort = (u16*)alloc(33554432);   // sorted V^T [4][16][32][64][128]
  u16*  Abf   = (u16*)alloc(33554432);   // bf16 input; later aliased as X
  u16*  Wqkvt = (u16*)alloc(6291456);    // [3072][1024] bf16 (B^T)
  u16*  Wot   = (u16*)alloc(2097152);    // [1024][1024] bf16 (B^T)
  float* sumk = (float*)alloc(524288);   // [4][32][1024]
  float* so   = (float*)alloc(16384);    // [4][32][32]
  float* perm = (float*)alloc(16384);    // [4][32][32]
  u16*  X = Abf;   // alias: attention output over Abf (dead after k_gemm_qkv)

  k_cast<<<16384, 256, 0, stream>>>(inq, Abf);
  k_transpose4<<<dim3(32, 32, 4), dim3(32, 32), 0, stream>>>(wq, wk, wv, wo, Wqkvt, Wot);
  k_gemm_qkv<<<dim3(24, 128), 256, 0, stream>>>(Abf, Wqkvt, bq, bk, bv, Qb, Kb, Vbt, sumk);
  k_sortmm<<<dim3(32, 4), 256, 0, stream>>>(sumk, wsort, bsort, so);
  k_sinkhorn<<<4, 32, 0, stream>>>(so, perm);
  k_mix<<<dim3(32, 32, 4), 256, 0, stream>>>(Kb, Vbt, perm, Ksort, Vsort);
  k_attn<<<dim3(32, 16, 4), 256, 0, stream>>>(Qb, Kb, Ksort, Vbt, Vsort, X);
  k_gemm_out<<<dim3(8, 128), 256, 0, stream>>>(X, Wot, bo, out);
}